// Round 4
// baseline (1183.941 us; speedup 1.0000x reference)
//
#include <hip/hip_runtime.h>
#include <hip/hip_bf16.h>

#define T_SEQ 256
#define BATCH 1024

typedef __attribute__((ext_vector_type(8))) short  short8;   // 8 bf16 (MFMA A/B frag)
typedef __attribute__((ext_vector_type(4))) float  floatx4;  // MFMA C/D frag
typedef unsigned short ushort_t;

template <int P> struct IC { static constexpr int v = P; };

__device__ __forceinline__ float sigmoid_fast(float x) {
    return 1.0f / (1.0f + __expf(-x));
}
__device__ __forceinline__ float tanh_fast(float x) {
    return 1.0f - 2.0f / (__expf(2.0f * x) + 1.0f);   // saturates correctly at +/-inf
}
__device__ __forceinline__ ushort_t f2bf(float f) {   // scalar RNE (weights init, h)
    union { float f; unsigned int u; } v; v.f = f;
    unsigned int r = v.u + 0x7FFFu + ((v.u >> 16) & 1u);
    return (ushort_t)(r >> 16);
}
__device__ __forceinline__ unsigned int pk_bf16(float a, float b) {  // packed RNE cvt
    union { __hip_bfloat162 h; unsigned int u; } v;
    v.h = __float22bfloat162_rn(make_float2(a, b));
    return v.u;
}
// Barrier WITHOUT vmcnt drain: LDS ordering only; global loads/stores stay in flight.
__device__ __forceinline__ void sync_lds() {
    asm volatile("s_waitcnt lgkmcnt(0)\n\ts_barrier" ::: "memory");
}

// ---------------- 4-wave kernel (layer 1: fp32 input, H=64) ----------------
// wave (mt,ug): gate tiles {g*UG+ug} share C lane-mapping -> i,f,g,o of a (row,unit)
// land in one lane; c/h update pure-register. h ping-pongs through LDS, 1 barrier/step.
// Bias pre-folded into acc init. All per-step addresses are stepping pointers.
template <int D, int H, bool SEQ_OUT>
__global__ __launch_bounds__(256, 1) void lstm_mfma4(
    const float* __restrict__ xin,
    const float* __restrict__ Wf, const float* __restrict__ Uf, const float* __restrict__ bgf,
    const float* __restrict__ Wb, const float* __restrict__ Ub, const float* __restrict__ bgb,
    void* __restrict__ outp)
{
    constexpr int UG  = H / 16;
    constexpr int MTB = 4 / UG;
    constexpr int RPB = 16 * MTB;
    constexpr int KSx = D / 32;
    constexpr int KSh = (H + 31) / 32;
    constexpr int KS  = KSx + KSh;
    constexpr int HP  = (H < 32 ? 32 : H) + 8;
    constexpr int G4  = 4 * H;

    const int tid  = threadIdx.x;
    const int wid  = tid >> 6;
    const int lane = tid & 63;
    const int lm   = lane & 15;
    const int lq   = lane >> 4;
    const int mt   = wid / UG;
    const int ug   = wid % UG;
    const int dir  = blockIdx.y;
    const int b0   = blockIdx.x * RPB;

    const float* W  = dir ? Wb  : Wf;
    const float* U  = dir ? Ub  : Uf;
    const float* bg = dir ? bgb : bgf;

    __shared__ __align__(16) ushort_t hbuf[2][RPB][HP];

    short8 bw[4][KS];
#pragma unroll
    for (int g = 0; g < 4; g++) {
        const int n = (g * UG + ug) * 16 + lm;
#pragma unroll
        for (int ks = 0; ks < KS; ks++) {
            short8 f;
#pragma unroll
            for (int e = 0; e < 8; e++) {
                const int k = ks * 32 + lq * 8 + e;
                float v = 0.0f;
                if (k < D)          v = W[k * G4 + n];
                else if (k < D + H) v = U[(k - D) * G4 + n];
                f[e] = (short)f2bf(v);
            }
            bw[g][ks] = f;
        }
    }
    float bb[4];
#pragma unroll
    for (int g = 0; g < 4; g++) bb[g] = bg[g * H + ug * 16 + lm];

    for (int idx = tid; idx < 2 * RPB * HP; idx += 256)
        ((ushort_t*)hbuf)[idx] = 0;

    float cst[4] = {0.f, 0.f, 0.f, 0.f};
    float hl[4]  = {0.f, 0.f, 0.f, 0.f};
    const int grow = b0 + mt * 16 + lm;
    const int t0   = dir ? T_SEQ - 1 : 0;

    // stepping pointers (no per-step 64-bit muls)
    const float* px = xin + ((size_t)grow * T_SEQ + t0) * D + lq * 8;
    const long   xstep = dir ? -(long)D : (long)D;
    ushort_t* pout = (ushort_t*)outp +
        ((size_t)t0 * BATCH + b0 + mt * 16 + lq * 4) * (2 * H) + dir * H + ug * 16 + lm;
    const long ostep = (dir ? -(long)BATCH : (long)BATCH) * (2 * H);

    float4 raw[2 * KSx];
    short8 frx[2][KSx];

    auto load_raw = [&]() {
#pragma unroll
        for (int ks = 0; ks < KSx; ks++) {
            raw[ks * 2 + 0] = *(const float4*)(px + ks * 32 + 0);
            raw[ks * 2 + 1] = *(const float4*)(px + ks * 32 + 4);
        }
        px += xstep;
    };
    auto conv = [&](auto pc) {
        constexpr int P = decltype(pc)::v;
#pragma unroll
        for (int ks = 0; ks < KSx; ks++) {
            union { short8 s; unsigned int u[4]; } f;
            const float* ra = (const float*)&raw[ks * 2];
#pragma unroll
            for (int e = 0; e < 4; e++) f.u[e] = pk_bf16(ra[2 * e], ra[2 * e + 1]);
            frx[P][ks] = f.s;
        }
    };

    load_raw(); conv(IC<0>{}); load_raw();
    __syncthreads();   // covers hbuf zero-init (once)

    auto step = [&](auto pc, int s) {
        constexpr int P = decltype(pc)::v;

        short8 fh[KSh];
#pragma unroll
        for (int ks = 0; ks < KSh; ks++)
            fh[ks] = *(const short8*)&hbuf[P][mt * 16 + lm][ks * 32 + lq * 8];

        floatx4 acc[4];
#pragma unroll
        for (int g = 0; g < 4; g++) acc[g] = (floatx4){bb[g], bb[g], bb[g], bb[g]};

#pragma unroll
        for (int ks = 0; ks < KSx; ks++)
#pragma unroll
            for (int g = 0; g < 4; g++)
                acc[g] = __builtin_amdgcn_mfma_f32_16x16x32_bf16(frx[P][ks], bw[g][ks], acc[g], 0, 0, 0);

        conv(IC<P ^ 1>{});                     // frx for s+1 (raw loaded at s-1)
        if (s + 2 < T_SEQ) load_raw();         // uniform scalar branch, no clamp

#pragma unroll
        for (int ks = 0; ks < KSh; ks++)
#pragma unroll
            for (int g = 0; g < 4; g++)
                acc[g] = __builtin_amdgcn_mfma_f32_16x16x32_bf16(fh[ks], bw[g][KSx + ks], acc[g], 0, 0, 0);

#pragma unroll
        for (int r = 0; r < 4; r++) {
            const float gi = sigmoid_fast(acc[0][r]);
            const float gf = sigmoid_fast(acc[1][r]);
            const float gg = tanh_fast   (acc[2][r]);
            const float go = sigmoid_fast(acc[3][r]);
            cst[r] = fmaf(gf, cst[r], gi * gg);
            const float h = go * tanh_fast(cst[r]);
            hl[r] = h;
            const ushort_t hw = f2bf(h);
            hbuf[P ^ 1][mt * 16 + lq * 4 + r][ug * 16 + lm] = hw;
            if (SEQ_OUT) pout[r * 2 * H] = hw;
        }
        pout += ostep;
        sync_lds();
    };

    for (int s = 0; s < T_SEQ; s += 2) {
        step(IC<0>{}, s);
        step(IC<1>{}, s + 1);
    }

    if (!SEQ_OUT) {
        float* op = (float*)outp;
#pragma unroll
        for (int r = 0; r < 4; r++)
            op[(size_t)(b0 + mt * 16 + lq * 4 + r) * (2 * H) + dir * H + ug * 16 + lm] = hl[r];
    }
}

// ---------------- single-wave kernel (layers 2,3: bf16 input) ----------------
// One wave = one 16-row batch tile, ALL gates (weights fit in VGPRs). h round-trips
// through wave-private LDS with lgkm ordering only — NO s_barrier for 256 steps.
template <int D, int H, bool SEQ_OUT>
__global__ __launch_bounds__(64, 1) void lstm_wave(
    const ushort_t* __restrict__ xin,
    const float* __restrict__ Wf, const float* __restrict__ Uf, const float* __restrict__ bgf,
    const float* __restrict__ Wb, const float* __restrict__ Ub, const float* __restrict__ bgb,
    void* __restrict__ outp)
{
    constexpr int UG  = H / 16;          // 2 (L2), 1 (L3)
    constexpr int KSx = D / 32;
    constexpr int KS  = KSx + 1;         // h fits one k-step (H<=32)
    constexpr int HP  = 40;              // padded h row stride (u16)
    constexpr int G4  = 4 * H;
    static_assert(H <= 32 && D % 32 == 0, "shape");

    const int lane = threadIdx.x;
    const int lm   = lane & 15;
    const int lq   = lane >> 4;
    const int dir  = blockIdx.y;
    const int b0   = blockIdx.x * 16;

    const float* W  = dir ? Wb  : Wf;
    const float* U  = dir ? Ub  : Uf;
    const float* bg = dir ? bgb : bgf;

    __shared__ __align__(16) ushort_t hbuf[16][HP];

    short8 bw[4][UG][KS];
    float  bb[4][UG];
#pragma unroll
    for (int g = 0; g < 4; g++)
#pragma unroll
        for (int u = 0; u < UG; u++) {
            const int n = g * H + u * 16 + lm;
            bb[g][u] = bg[n];
#pragma unroll
            for (int ks = 0; ks < KS; ks++) {
                short8 f;
#pragma unroll
                for (int e = 0; e < 8; e++) {
                    const int k = ks * 32 + lq * 8 + e;
                    float v = 0.0f;
                    if (k < D)          v = W[k * G4 + n];
                    else if (k < D + H) v = U[(k - D) * G4 + n];
                    f[e] = (short)f2bf(v);
                }
                bw[g][u][ks] = f;
            }
        }

    for (int idx = lane; idx < 16 * HP; idx += 64)
        ((ushort_t*)hbuf)[idx] = 0;      // h0 = 0 (+ pad stays 0); same-wave lgkm ordering

    float cst[4 * UG], hl[4 * UG];
#pragma unroll
    for (int q = 0; q < 4 * UG; q++) { cst[q] = 0.f; hl[q] = 0.f; }

    const int t0 = dir ? T_SEQ - 1 : 0;
    const ushort_t* px = xin + ((size_t)t0 * BATCH + b0 + lm) * D + lq * 8;
    const long xstep = (dir ? -(long)BATCH : (long)BATCH) * D;
    ushort_t* pout = (ushort_t*)outp +
        ((size_t)t0 * BATCH + b0 + lq * 4) * (2 * H) + dir * H + lm;
    const long ostep = (dir ? -(long)BATCH : (long)BATCH) * (2 * H);

    short8 frx[2][KSx];
    auto load_frx = [&](auto pc) {
        constexpr int P = decltype(pc)::v;
#pragma unroll
        for (int ks = 0; ks < KSx; ks++)
            frx[P][ks] = *(const short8*)(px + ks * 32);
        px += xstep;
    };
    load_frx(IC<0>{});
    load_frx(IC<1>{});

    auto step = [&](auto pc, int s) {
        constexpr int P = decltype(pc)::v;

        floatx4 acc[4][UG];
#pragma unroll
        for (int g = 0; g < 4; g++)
#pragma unroll
            for (int u = 0; u < UG; u++)
                acc[g][u] = (floatx4){bb[g][u], bb[g][u], bb[g][u], bb[g][u]};

        // x-part (register A-frags, no LDS dependency)
#pragma unroll
        for (int ks = 0; ks < KSx; ks++)
#pragma unroll
            for (int g = 0; g < 4; g++)
#pragma unroll
                for (int u = 0; u < UG; u++)
                    acc[g][u] = __builtin_amdgcn_mfma_f32_16x16x32_bf16(frx[P][ks], bw[g][u][KSx ? ks : 0], acc[g][u], 0, 0, 0);

        if (s + 2 < T_SEQ) load_frx(pc);   // uniform branch; refills the buffer just consumed

        // h A-frag (aliases prev step's ds_write; compiler lgkm-orders; no barrier)
        const short8 fh = *(const short8*)&hbuf[lm][lq * 8];
#pragma unroll
        for (int g = 0; g < 4; g++)
#pragma unroll
            for (int u = 0; u < UG; u++)
                acc[g][u] = __builtin_amdgcn_mfma_f32_16x16x32_bf16(fh, bw[g][u][KSx], acc[g][u], 0, 0, 0);

#pragma unroll
        for (int u = 0; u < UG; u++)
#pragma unroll
            for (int r = 0; r < 4; r++) {
                const int q = u * 4 + r;
                const float gi = sigmoid_fast(acc[0][u][r]);
                const float gf = sigmoid_fast(acc[1][u][r]);
                const float gg = tanh_fast   (acc[2][u][r]);
                const float go = sigmoid_fast(acc[3][u][r]);
                cst[q] = fmaf(gf, cst[q], gi * gg);
                const float h = go * tanh_fast(cst[q]);
                hl[q] = h;
                const ushort_t hw = f2bf(h);
                hbuf[lq * 4 + r][u * 16 + lm] = hw;
                if (SEQ_OUT) pout[r * 2 * H + u * 16] = hw;
            }
        pout += ostep;
    };

    for (int s = 0; s < T_SEQ; s += 2) {
        step(IC<0>{}, s);
        step(IC<1>{}, s + 1);
    }

    if (!SEQ_OUT) {
        float* op = (float*)outp;
#pragma unroll
        for (int u = 0; u < UG; u++)
#pragma unroll
            for (int r = 0; r < 4; r++)
                op[(size_t)(b0 + lq * 4 + r) * (2 * H) + dir * H + u * 16 + lm] = hl[u * 4 + r];
    }
}

// Dense head: relu6(x@Wd1+bd1) @ Wd2 + bd2 -> softmax(2). One row per thread.
__global__ __launch_bounds__(256) void dense_head(
    const float* __restrict__ h3, const float* __restrict__ Wd1, const float* __restrict__ bd1,
    const float* __restrict__ Wd2, const float* __restrict__ bd2, float* __restrict__ out)
{
    const int b = blockIdx.x * blockDim.x + threadIdx.x;
    if (b >= BATCH) return;
    float x[32];
#pragma unroll
    for (int k = 0; k < 32; k++) x[k] = h3[b * 32 + k];
    float y[16];
#pragma unroll
    for (int jj = 0; jj < 16; jj++) {
        float a = bd1[jj];
#pragma unroll
        for (int k = 0; k < 32; k++) a = fmaf(x[k], Wd1[k * 16 + jj], a);
        y[jj] = fminf(fmaxf(a, 0.0f), 6.0f);
    }
    float l0 = bd2[0], l1 = bd2[1];
#pragma unroll
    for (int k = 0; k < 16; k++) {
        l0 = fmaf(y[k], Wd2[k * 2 + 0], l0);
        l1 = fmaf(y[k], Wd2[k * 2 + 1], l1);
    }
    const float m = fmaxf(l0, l1);
    const float e0 = __expf(l0 - m), e1 = __expf(l1 - m);
    const float inv = 1.0f / (e0 + e1);
    out[b * 2 + 0] = e0 * inv;
    out[b * 2 + 1] = e1 * inv;
}

extern "C" void kernel_launch(void* const* d_in, const int* in_sizes, int n_in,
                              void* d_out, int out_size, void* d_ws, size_t ws_size,
                              hipStream_t stream)
{
    const float* x   = (const float*)d_in[0];
    const float* W1f = (const float*)d_in[1];
    const float* U1f = (const float*)d_in[2];
    const float* b1f = (const float*)d_in[3];
    const float* W1b = (const float*)d_in[4];
    const float* U1b = (const float*)d_in[5];
    const float* b1b = (const float*)d_in[6];
    const float* W2f = (const float*)d_in[7];
    const float* U2f = (const float*)d_in[8];
    const float* b2f = (const float*)d_in[9];
    const float* W2b = (const float*)d_in[10];
    const float* U2b = (const float*)d_in[11];
    const float* b2b = (const float*)d_in[12];
    const float* W3f = (const float*)d_in[13];
    const float* U3f = (const float*)d_in[14];
    const float* b3f = (const float*)d_in[15];
    const float* W3b = (const float*)d_in[16];
    const float* U3b = (const float*)d_in[17];
    const float* b3b = (const float*)d_in[18];
    const float* Wd1 = (const float*)d_in[19];
    const float* bd1 = (const float*)d_in[20];
    const float* Wd2 = (const float*)d_in[21];
    const float* bd2 = (const float*)d_in[22];

    char* ws = (char*)d_ws;
    void* l1out = (void*)ws;                                  // [T][B][128] bf16 = 64 MB
    void* l2out = (void*)(ws + (size_t)64 * 1024 * 1024);     // [T][B][64]  bf16 = 32 MB
    float* h3   = (float*)(ws + (size_t)96 * 1024 * 1024);    // [B][32] fp32
    float* out  = (float*)d_out;

    lstm_mfma4<64, 64, true>
        <<<dim3(BATCH / 16, 2), 256, 0, stream>>>(x, W1f, U1f, b1f, W1b, U1b, b1b, l1out);
    lstm_wave<128, 32, true>
        <<<dim3(BATCH / 16, 2), 64, 0, stream>>>((const ushort_t*)l1out, W2f, U2f, b2f, W2b, U2b, b2b, l2out);
    lstm_wave<64, 16, false>
        <<<dim3(BATCH / 16, 2), 64, 0, stream>>>((const ushort_t*)l2out, W3f, U3f, b3f, W3b, U3b, b3b, h3);
    dense_head<<<dim3(BATCH / 256), 256, 0, stream>>>(h3, Wd1, bd1, Wd2, bd2, out);
}

// Round 5
// 647.289 us; speedup vs baseline: 1.8291x; 1.8291x over previous
//
#include <hip/hip_runtime.h>
#include <hip/hip_bf16.h>

#define T_SEQ 256
#define BATCH 1024

typedef __attribute__((ext_vector_type(8))) short  short8;   // 8 bf16 (MFMA A/B frag)
typedef __attribute__((ext_vector_type(4))) float  floatx4;  // MFMA C/D frag
typedef unsigned short ushort_t;

template <int P> struct IC { static constexpr int v = P; };

__device__ __forceinline__ float exp2_fast(float x) {
#if __has_builtin(__builtin_amdgcn_exp2f)
    return __builtin_amdgcn_exp2f(x);
#else
    float r; asm("v_exp_f32 %0, %1" : "=v"(r) : "v"(x)); return r;
#endif
}
__device__ __forceinline__ float rcp_fast(float x) {
#if __has_builtin(__builtin_amdgcn_rcpf)
    return __builtin_amdgcn_rcpf(x);
#else
    float r; asm("v_rcp_f32 %0, %1" : "=v"(r) : "v"(x)); return r;
#endif
}
__device__ __forceinline__ ushort_t f2bf(float f) {
    union { float f; unsigned int u; } v; v.f = f;
    unsigned int r = v.u + 0x7FFFu + ((v.u >> 16) & 1u);   // RNE
    return (ushort_t)(r >> 16);
}
__device__ __forceinline__ unsigned int pk_bf16(float a, float b) {
    union { __hip_bfloat162 h; unsigned int u; } v;
    v.h = __float22bfloat162_rn(make_float2(a, b));
    return v.u;
}
// Barrier WITHOUT vmcnt drain: LDS ordering only; global loads/stores stay in flight.
__device__ __forceinline__ void sync_lds() {
    asm volatile("s_waitcnt lgkmcnt(0)\n\ts_barrier" ::: "memory");
}

// Producer/consumer persistent LSTM layer. Block = 8 waves (512 thr):
//   waves 0-3 (consumers): recurrence only — ring read + h-MFMA + activation.
//   waves 4-7 (producers): xz = x*W + b, 2 steps ahead, into a 4-slot LDS ring
//     in C-frag lane order (consumer reads its 16 floats as 4x ds_read_b128).
// Weights pre-scaled: i,f,o by -log2e (sigmoid = rcp(1+exp2(z))); g by 2*log2e
// (tanh = 1 - 2*rcp(1+exp2(z))). All divides -> v_rcp_f32.
// Frag maps (mfma_f32_16x16x32_bf16, HW-verified): A[m=lane&15][k=(lane>>4)*8+e],
// B[k=(lane>>4)*8+e][n=lane&15], C: col=lane&15, row=(lane>>4)*4+reg.
template <int D, int H, bool IS_FIRST, bool SEQ_OUT>
__global__ __launch_bounds__(512, 2) void lstm_pc(
    const void* __restrict__ xin,
    const float* __restrict__ Wf, const float* __restrict__ Uf, const float* __restrict__ bgf,
    const float* __restrict__ Wb, const float* __restrict__ Ub, const float* __restrict__ bgb,
    void* __restrict__ outp)
{
    constexpr int UG  = H / 16;                  // unit groups: 4/2/1
    constexpr int MTC = 4 / UG;                  // m-tiles per block: 1/2/4
    constexpr int RPB = 16 * MTC;                // rows per block: 16/32/64
    constexpr int KSx = D / 32;
    constexpr int KSh = (H + 31) / 32;
    constexpr int HP  = (H < 32 ? 32 : H) + 8;   // padded h row stride (u16)
    constexpr int G4  = 4 * H;
    constexpr int RS  = 20;                      // ring lane stride (dwords; 80B staggers banks)
    static_assert(UG >= 1 && D % 32 == 0 && T_SEQ % 4 == 0, "shape");

    const int  tid  = threadIdx.x;
    const int  wid  = tid >> 6;
    const bool cons = wid < 4;
    const int  w4   = wid & 3;                   // consumer id / producer's served consumer
    const int  lane = tid & 63;
    const int  lm   = lane & 15;
    const int  lq   = lane >> 4;
    const int  mt   = w4 / UG;
    const int  ug   = w4 % UG;
    const int  dir  = blockIdx.y;
    const int  b0   = blockIdx.x * RPB;

    const float* W  = dir ? Wb  : Wf;
    const float* U  = dir ? Ub  : Uf;
    const float* bg = dir ? bgb : bgf;

    __shared__ __align__(16) float    ring[4 * 4 * 64 * RS];   // 80 KB
    __shared__ __align__(16) ushort_t hbuf[2][RPB][HP];

    constexpr float NL2E = -1.4426950408889634f;   // -log2(e)
    constexpr float L2E2 =  2.8853900817779268f;   // 2*log2(e)

    float* const rbase = &ring[(w4 * 64 + lane) * RS];
    auto rptr = [&](int slot) -> float* { return rbase + slot * (4 * 64 * RS); };

    // zero h ping-pong buffers (h0 = 0; k-padding stays 0)
    for (int idx = tid; idx < 2 * RPB * HP; idx += 512)
        ((ushort_t*)hbuf)[idx] = 0;

    const int t0 = dir ? T_SEQ - 1 : 0;

    if (cons) {
        // ---------------- consumer ----------------
        short8 bwh[4][KSh];
#pragma unroll
        for (int g = 0; g < 4; g++) {
            const float sc = (g == 2) ? L2E2 : NL2E;
            const int n = (g * UG + ug) * 16 + lm;
#pragma unroll
            for (int ks = 0; ks < KSh; ks++) {
                short8 f;
#pragma unroll
                for (int e = 0; e < 8; e++) {
                    const int k = ks * 32 + lq * 8 + e;
                    f[e] = (short)f2bf(k < H ? sc * U[k * G4 + n] : 0.0f);
                }
                bwh[g][ks] = f;
            }
        }

        float cst[4] = {0.f, 0.f, 0.f, 0.f};
        float hl[4]  = {0.f, 0.f, 0.f, 0.f};
        ushort_t* pout = (ushort_t*)outp +
            ((size_t)t0 * BATCH + b0 + mt * 16 + lq * 4) * (2 * H) + dir * H + ug * 16 + lm;
        const long ostep = (dir ? -(long)BATCH : (long)BATCH) * (2 * H);

        __syncthreads();   // pair with producer prologue (slots 0,1 + hbuf zeros)

        auto cstep = [&](auto pc, int slot) {
            constexpr int P = decltype(pc)::v;
            const float* rp = rptr(slot);

            short8 fh[KSh];
#pragma unroll
            for (int ks = 0; ks < KSh; ks++)
                fh[ks] = *(const short8*)&hbuf[P][mt * 16 + lm][ks * 32 + lq * 8];

            floatx4 acc[4];
#pragma unroll
            for (int g = 0; g < 4; g++) acc[g] = *(const floatx4*)(rp + g * 4);

#pragma unroll
            for (int ks = 0; ks < KSh; ks++)
#pragma unroll
                for (int g = 0; g < 4; g++)
                    acc[g] = __builtin_amdgcn_mfma_f32_16x16x32_bf16(fh[ks], bwh[g][ks], acc[g], 0, 0, 0);

#pragma unroll
            for (int r = 0; r < 4; r++) {
                const float gi = rcp_fast(1.0f + exp2_fast(acc[0][r]));          // sigmoid
                const float gf = rcp_fast(1.0f + exp2_fast(acc[1][r]));
                const float gg = 1.0f - 2.0f * rcp_fast(1.0f + exp2_fast(acc[2][r]));  // tanh
                const float go = rcp_fast(1.0f + exp2_fast(acc[3][r]));
                cst[r] = fmaf(gf, cst[r], gi * gg);
                const float tc = 1.0f - 2.0f * rcp_fast(1.0f + exp2_fast(L2E2 * cst[r]));
                const float h = go * tc;
                hl[r] = h;
                const ushort_t hw = f2bf(h);
                hbuf[P ^ 1][mt * 16 + lq * 4 + r][ug * 16 + lm] = hw;
                if (SEQ_OUT) pout[r * 2 * H] = hw;
            }
            pout += ostep;
            sync_lds();
        };

        for (int s = 0; s < T_SEQ; s += 4) {
            cstep(IC<0>{}, 0);
            cstep(IC<1>{}, 1);
            cstep(IC<0>{}, 2);
            cstep(IC<1>{}, 3);
        }

        if (!SEQ_OUT) {
            float* op = (float*)outp;
#pragma unroll
            for (int r = 0; r < 4; r++)
                op[(size_t)(b0 + mt * 16 + lq * 4 + r) * (2 * H) + dir * H + ug * 16 + lm] = hl[r];
        }
    } else {
        // ---------------- producer ----------------
        short8 bwx[4][KSx];
        float  bb[4];
#pragma unroll
        for (int g = 0; g < 4; g++) {
            const float sc = (g == 2) ? L2E2 : NL2E;
            const int n = (g * UG + ug) * 16 + lm;
            bb[g] = sc * bg[n];
#pragma unroll
            for (int ks = 0; ks < KSx; ks++) {
                short8 f;
#pragma unroll
                for (int e = 0; e < 8; e++)
                    f[e] = (short)f2bf(sc * W[(ks * 32 + lq * 8 + e) * G4 + n]);
                bwx[g][ks] = f;
            }
        }

        const int grow = b0 + mt * 16 + lm;
        const float*    pxf = (const float*)xin   + ((size_t)grow * T_SEQ + t0) * D + lq * 8;
        const ushort_t* pxb = (const ushort_t*)xin + ((size_t)t0 * BATCH + grow) * D + lq * 8;
        const long xstepf = dir ? -(long)D : (long)D;
        const long xstepb = (dir ? -(long)BATCH : (long)BATCH) * D;

        float4 raw[2][2 * KSx];
        short8 frx[2][KSx];

        auto pload = [&](auto pc) {
            constexpr int P = decltype(pc)::v;
            if (IS_FIRST) {
#pragma unroll
                for (int ks = 0; ks < KSx; ks++) {
                    raw[P][ks * 2 + 0] = *(const float4*)(pxf + ks * 32 + 0);
                    raw[P][ks * 2 + 1] = *(const float4*)(pxf + ks * 32 + 4);
                }
                pxf += xstepf;
            } else {
#pragma unroll
                for (int ks = 0; ks < KSx; ks++)
                    frx[P][ks] = *(const short8*)(pxb + ks * 32);
                pxb += xstepb;
            }
        };
        auto pcompute = [&](auto pc, int slot) {
            constexpr int P = decltype(pc)::v;
            short8 av[KSx];
            if (IS_FIRST) {
#pragma unroll
                for (int ks = 0; ks < KSx; ks++) {
                    union { short8 s; unsigned int u[4]; } f;
                    const float* ra = (const float*)&raw[P][ks * 2];
#pragma unroll
                    for (int e = 0; e < 4; e++) f.u[e] = pk_bf16(ra[2 * e], ra[2 * e + 1]);
                    av[ks] = f.s;
                }
            } else {
#pragma unroll
                for (int ks = 0; ks < KSx; ks++) av[ks] = frx[P][ks];
            }
            floatx4 acc[4];
#pragma unroll
            for (int g = 0; g < 4; g++) acc[g] = (floatx4){bb[g], bb[g], bb[g], bb[g]};
#pragma unroll
            for (int ks = 0; ks < KSx; ks++)
#pragma unroll
                for (int g = 0; g < 4; g++)
                    acc[g] = __builtin_amdgcn_mfma_f32_16x16x32_bf16(av[ks], bwx[g][ks], acc[g], 0, 0, 0);
            float* rp = rptr(slot);
#pragma unroll
            for (int g = 0; g < 4; g++) *(floatx4*)(rp + g * 4) = acc[g];
        };

        // prologue: xz(0)->slot0, xz(1)->slot1; x(2),x(3) in flight
        pload(IC<0>{});            // x(0)
        pload(IC<1>{});            // x(1)
        pcompute(IC<0>{}, 0);
        pcompute(IC<1>{}, 1);
        pload(IC<0>{});            // x(2)
        pload(IC<1>{});            // x(3)
        __syncthreads();

        auto pstep = [&](auto pc, int slot, int s) {
            if (s + 2 < T_SEQ) pcompute(pc, slot);
            if (s + 4 < T_SEQ) pload(pc);
            sync_lds();
        };

        for (int s = 0; s < T_SEQ; s += 4) {
            pstep(IC<0>{}, 2, s);
            pstep(IC<1>{}, 3, s + 1);
            pstep(IC<0>{}, 0, s + 2);
            pstep(IC<1>{}, 1, s + 3);
        }
    }
}

// Dense head: relu6(x@Wd1+bd1) @ Wd2 + bd2 -> softmax(2). One row per thread.
__global__ __launch_bounds__(256) void dense_head(
    const float* __restrict__ h3, const float* __restrict__ Wd1, const float* __restrict__ bd1,
    const float* __restrict__ Wd2, const float* __restrict__ bd2, float* __restrict__ out)
{
    const int b = blockIdx.x * blockDim.x + threadIdx.x;
    if (b >= BATCH) return;
    float x[32];
#pragma unroll
    for (int k = 0; k < 32; k++) x[k] = h3[b * 32 + k];
    float y[16];
#pragma unroll
    for (int jj = 0; jj < 16; jj++) {
        float a = bd1[jj];
#pragma unroll
        for (int k = 0; k < 32; k++) a = fmaf(x[k], Wd1[k * 16 + jj], a);
        y[jj] = fminf(fmaxf(a, 0.0f), 6.0f);
    }
    float l0 = bd2[0], l1 = bd2[1];
#pragma unroll
    for (int k = 0; k < 16; k++) {
        l0 = fmaf(y[k], Wd2[k * 2 + 0], l0);
        l1 = fmaf(y[k], Wd2[k * 2 + 1], l1);
    }
    const float m = fmaxf(l0, l1);
    const float e0 = __expf(l0 - m), e1 = __expf(l1 - m);
    const float inv = 1.0f / (e0 + e1);
    out[b * 2 + 0] = e0 * inv;
    out[b * 2 + 1] = e1 * inv;
}

extern "C" void kernel_launch(void* const* d_in, const int* in_sizes, int n_in,
                              void* d_out, int out_size, void* d_ws, size_t ws_size,
                              hipStream_t stream)
{
    const float* x   = (const float*)d_in[0];
    const float* W1f = (const float*)d_in[1];
    const float* U1f = (const float*)d_in[2];
    const float* b1f = (const float*)d_in[3];
    const float* W1b = (const float*)d_in[4];
    const float* U1b = (const float*)d_in[5];
    const float* b1b = (const float*)d_in[6];
    const float* W2f = (const float*)d_in[7];
    const float* U2f = (const float*)d_in[8];
    const float* b2f = (const float*)d_in[9];
    const float* W2b = (const float*)d_in[10];
    const float* U2b = (const float*)d_in[11];
    const float* b2b = (const float*)d_in[12];
    const float* W3f = (const float*)d_in[13];
    const float* U3f = (const float*)d_in[14];
    const float* b3f = (const float*)d_in[15];
    const float* W3b = (const float*)d_in[16];
    const float* U3b = (const float*)d_in[17];
    const float* b3b = (const float*)d_in[18];
    const float* Wd1 = (const float*)d_in[19];
    const float* bd1 = (const float*)d_in[20];
    const float* Wd2 = (const float*)d_in[21];
    const float* bd2 = (const float*)d_in[22];

    char* ws = (char*)d_ws;
    void* l1out = (void*)ws;                                  // [T][B][128] bf16 = 64 MB
    void* l2out = (void*)(ws + (size_t)64 * 1024 * 1024);     // [T][B][64]  bf16 = 32 MB
    float* h3   = (float*)(ws + (size_t)96 * 1024 * 1024);    // [B][32] fp32
    float* out  = (float*)d_out;

    lstm_pc<64, 64, true, true>       // UG=4, RPB=16
        <<<dim3(BATCH / 16, 2), 512, 0, stream>>>(x, W1f, U1f, b1f, W1b, U1b, b1b, l1out);
    lstm_pc<128, 32, false, true>     // UG=2, RPB=32
        <<<dim3(BATCH / 32, 2), 512, 0, stream>>>(l1out, W2f, U2f, b2f, W2b, U2b, b2b, l2out);
    lstm_pc<64, 16, false, false>     // UG=1, RPB=64
        <<<dim3(BATCH / 64, 2), 512, 0, stream>>>(l2out, W3f, U3f, b3f, W3b, U3b, b3b, h3);
    dense_head<<<dim3(BATCH / 256), 256, 0, stream>>>(h3, Wd1, bd1, Wd2, bd2, out);
}

// Round 7
// 518.295 us; speedup vs baseline: 2.2843x; 1.2489x over previous
//
#include <hip/hip_runtime.h>
#include <hip/hip_bf16.h>

#define T_SEQ 256
#define BATCH 1024

typedef __attribute__((ext_vector_type(8))) short  short8;   // 8 bf16 (MFMA A/B frag)
typedef __attribute__((ext_vector_type(4))) float  floatx4;  // MFMA C/D frag
typedef unsigned short ushort_t;
typedef unsigned int   uint_t;

template <int P> struct IC { static constexpr int v = P; };

constexpr float NL2E = -1.4426950408889634f;   // -log2(e): sigmoid = rcp(1+exp2(z))
constexpr float L2E2 =  2.8853900817779268f;   // 2*log2(e): tanh = 1-2*rcp(1+exp2(x))

__device__ __forceinline__ float exp2_fast(float x) {
    float r; asm("v_exp_f32 %0, %1" : "=v"(r) : "v"(x)); return r;
}
__device__ __forceinline__ float rcp_fast(float x) {
    float r; asm("v_rcp_f32 %0, %1" : "=v"(r) : "v"(x)); return r;
}
__device__ __forceinline__ ushort_t f2bf(float f) {
    union { float f; uint_t u; } v; v.f = f;
    uint_t r = v.u + 0x7FFFu + ((v.u >> 16) & 1u);   // RNE
    return (ushort_t)(r >> 16);
}
__device__ __forceinline__ uint_t pk_bf16(float a, float b) {
    union { __hip_bfloat162 h; uint_t u; } v;
    v.h = __float22bfloat162_rn(make_float2(a, b));
    return v.u;
}
// Barrier WITHOUT vmcnt drain: LDS ordering only; global loads/stores stay in flight.
__device__ __forceinline__ void sync_lds() {
    asm volatile("s_waitcnt lgkmcnt(0)\n\ts_barrier" ::: "memory");
}

// Fused persistent LSTM layer (one kernel per layer, NO xz materialization).
// Block = UG waves x 16 batch rows; wave ug owns gate tiles {g*UG+ug} so all 4 gates
// of a (row,unit) land in one lane -> pure-register c/h update.
//  - x A-frags prefetched 4 steps deep in a register ring (fp32->bf16 packed conv
//    for layer 1), x-MFMAs in-wave: no xz buffer, no producer waves.
//  - weights pre-scaled (-log2e / 2log2e): all activations are rcp(1+exp2(z)).
//  - h ping-pongs in LDS; one lgkm-only barrier per step (none when UG==1).
//  - 4-phase unroll => distinct store-data registers; vmcnt waits look 4 steps back.
// Frag maps (mfma_f32_16x16x32_bf16, HW-verified): A[m=lane&15][k=(lane>>4)*8+e],
// B[k=(lane>>4)*8+e][n=lane&15], C: col=lane&15, row=(lane>>4)*4+reg.
template <int D, int H, bool IS_FIRST, bool SEQ_OUT>
__global__ __launch_bounds__(64 * (H / 16), 1) void lstm_fused(
    const void* __restrict__ xin,
    const float* __restrict__ Wf, const float* __restrict__ Uf, const float* __restrict__ bgf,
    const float* __restrict__ Wb, const float* __restrict__ Ub, const float* __restrict__ bgb,
    void* __restrict__ outp)
{
    constexpr int UG  = H / 16;                  // waves per block: 4/2/1
    constexpr int KSx = D / 32;
    constexpr int KSh = (H + 31) / 32;
    constexpr int KS  = KSx + KSh;
    constexpr int HP  = (H < 32 ? 32 : H) + 8;   // padded h row stride (u16), 16B-aligned
    constexpr int G4  = 4 * H;
    constexpr int NTH = 64 * UG;
    static_assert(D % 32 == 0 && T_SEQ % 4 == 0, "shape");

    const int tid  = threadIdx.x;
    const int ug   = tid >> 6;
    const int lane = tid & 63;
    const int lm   = lane & 15;
    const int lq   = lane >> 4;
    const int dir  = blockIdx.y;
    const int b0   = blockIdx.x * 16;

    const float* W  = dir ? Wb  : Wf;
    const float* U  = dir ? Ub  : Uf;
    const float* bg = dir ? bgb : bgf;

    __shared__ __align__(16) ushort_t hbuf[2][16][HP];

    // ---- one-time: combined [W;U] B-frags (pre-scaled) + bias ----
    short8 bw[4][KS];
    float  bb[4];
#pragma unroll
    for (int g = 0; g < 4; g++) {
        const float sc = (g == 2) ? L2E2 : NL2E;
        const int n = g * H + ug * 16 + lm;
        bb[g] = sc * bg[n];
#pragma unroll
        for (int ks = 0; ks < KS; ks++) {
            short8 f;
#pragma unroll
            for (int e = 0; e < 8; e++) {
                const int k = ks * 32 + lq * 8 + e;
                float v = 0.0f;
                if (k < D)          v = W[k * G4 + n];
                else if (k < D + H) v = U[(k - D) * G4 + n];
                f[e] = (short)f2bf(sc * v);
            }
            bw[g][ks] = f;
        }
    }

    for (int idx = tid; idx < 2 * 16 * HP; idx += NTH)
        ((ushort_t*)hbuf)[idx] = 0;   // h0 = 0; k-padding stays 0 forever

    float cst[4] = {0.f, 0.f, 0.f, 0.f};
    float hl[4]  = {0.f, 0.f, 0.f, 0.f};

    const int t0 = dir ? T_SEQ - 1 : 0;
    // stepping pointers (no per-step 64-bit muls)
    const float*    pxf = (const float*)xin + ((size_t)(b0 + lm) * T_SEQ + t0) * D + lq * 8;
    const ushort_t* pxb = (const ushort_t*)xin + ((size_t)t0 * BATCH + b0 + lm) * D + lq * 8;
    const long xstepf = dir ? -(long)D : (long)D;
    const long xstepb = (dir ? -(long)BATCH : (long)BATCH) * D;
    ushort_t* pout = (ushort_t*)outp +
        ((size_t)t0 * BATCH + b0 + lq * 4) * (2 * H) + dir * H + ug * 16 + lm;
    const long ostep = (dir ? -(long)BATCH : (long)BATCH) * (2 * H);

    // x prefetch ring, depth 4
    float4 rawf[4][2 * KSx];   // layer-1 path (fp32 input); DCE'd otherwise
    short8 rawb[4][KSx];       // bf16 path

    auto load_slot = [&](auto sl_) {
        constexpr int SL = decltype(sl_)::v;
        if (IS_FIRST) {
#pragma unroll
            for (int ks = 0; ks < KSx; ks++) {
                rawf[SL][2 * ks + 0] = *(const float4*)(pxf + ks * 32 + 0);
                rawf[SL][2 * ks + 1] = *(const float4*)(pxf + ks * 32 + 4);
            }
            pxf += xstepf;
        } else {
#pragma unroll
            for (int ks = 0; ks < KSx; ks++)
                rawb[SL][ks] = *(const short8*)(pxb + ks * 32);
            pxb += xstepb;
        }
    };

    load_slot(IC<0>{}); load_slot(IC<1>{}); load_slot(IC<2>{}); load_slot(IC<3>{});
    __syncthreads();   // hbuf zeros visible (full barrier once; drains prologue loads, fine)

    auto step = [&](auto p_, auto sl_, int s) {
        constexpr int P  = decltype(p_)::v;
        constexpr int SL = decltype(sl_)::v;

        // h A-frags from LDS (issued first; x-MFMAs overlap the lgkm latency)
        short8 fh[KSh];
#pragma unroll
        for (int ks = 0; ks < KSh; ks++)
            fh[ks] = *(const short8*)&hbuf[P][lm][ks * 32 + lq * 8];

        floatx4 acc[4];
#pragma unroll
        for (int g = 0; g < 4; g++) acc[g] = (floatx4){bb[g], bb[g], bb[g], bb[g]};

        // x A-frags from the register ring (packed fp32->bf16 conv on layer 1)
        short8 av[KSx];
        if (IS_FIRST) {
#pragma unroll
            for (int ks = 0; ks < KSx; ks++) {
                union { short8 s; uint_t u[4]; } f;
                const float* ra = (const float*)&rawf[SL][2 * ks];
#pragma unroll
                for (int e = 0; e < 4; e++) f.u[e] = pk_bf16(ra[2 * e], ra[2 * e + 1]);
                av[ks] = f.s;
            }
        } else {
#pragma unroll
            for (int ks = 0; ks < KSx; ks++) av[ks] = rawb[SL][ks];
        }

#pragma unroll
        for (int ks = 0; ks < KSx; ks++)
#pragma unroll
            for (int g = 0; g < 4; g++)
                acc[g] = __builtin_amdgcn_mfma_f32_16x16x32_bf16(av[ks], bw[g][ks], acc[g], 0, 0, 0);

        if (s + 4 < T_SEQ) load_slot(sl_);   // refill consumed slot (uniform branch)

#pragma unroll
        for (int ks = 0; ks < KSh; ks++)
#pragma unroll
            for (int g = 0; g < 4; g++)
                acc[g] = __builtin_amdgcn_mfma_f32_16x16x32_bf16(fh[ks], bw[g][KSx + ks], acc[g], 0, 0, 0);

        // gates + c/h update, pure-register (pre-scaled z)
#pragma unroll
        for (int r = 0; r < 4; r++) {
            const float gi = rcp_fast(1.0f + exp2_fast(acc[0][r]));
            const float gf = rcp_fast(1.0f + exp2_fast(acc[1][r]));
            const float gg = 1.0f - 2.0f * rcp_fast(1.0f + exp2_fast(acc[2][r]));
            const float go = rcp_fast(1.0f + exp2_fast(acc[3][r]));
            cst[r] = fmaf(gf, cst[r], gi * gg);
            const float tc = 1.0f - 2.0f * rcp_fast(1.0f + exp2_fast(L2E2 * cst[r]));
            const float h = go * tc;
            hl[r] = h;
            const ushort_t hw = f2bf(h);
            hbuf[P ^ 1][lq * 4 + r][ug * 16 + lm] = hw;
            if (SEQ_OUT) pout[r * 2 * H] = hw;
        }
        pout += ostep;
        if (UG > 1) sync_lds();   // lgkm-only; single-wave layer needs no barrier
    };

    for (int s = 0; s < T_SEQ; s += 4) {
        step(IC<0>{}, IC<0>{}, s);
        step(IC<1>{}, IC<1>{}, s + 1);
        step(IC<0>{}, IC<2>{}, s + 2);
        step(IC<1>{}, IC<3>{}, s + 3);
    }

    if (!SEQ_OUT) {
        float* op = (float*)outp;
#pragma unroll
        for (int r = 0; r < 4; r++)
            op[(size_t)(b0 + lq * 4 + r) * (2 * H) + dir * H + ug * 16 + lm] = hl[r];
    }
}

// Dense head: relu6(x@Wd1+bd1) @ Wd2 + bd2 -> softmax(2). One row per thread.
__global__ __launch_bounds__(256) void dense_head(
    const float* __restrict__ h3, const float* __restrict__ Wd1, const float* __restrict__ bd1,
    const float* __restrict__ Wd2, const float* __restrict__ bd2, float* __restrict__ out)
{
    const int b = blockIdx.x * blockDim.x + threadIdx.x;
    if (b >= BATCH) return;
    float x[32];
#pragma unroll
    for (int k = 0; k < 32; k++) x[k] = h3[b * 32 + k];
    float y[16];
#pragma unroll
    for (int jj = 0; jj < 16; jj++) {
        float a = bd1[jj];
#pragma unroll
        for (int k = 0; k < 32; k++) a = fmaf(x[k], Wd1[k * 16 + jj], a);
        y[jj] = fminf(fmaxf(a, 0.0f), 6.0f);
    }
    float l0 = bd2[0], l1 = bd2[1];
#pragma unroll
    for (int k = 0; k < 16; k++) {
        l0 = fmaf(y[k], Wd2[k * 2 + 0], l0);
        l1 = fmaf(y[k], Wd2[k * 2 + 1], l1);
    }
    const float m = fmaxf(l0, l1);
    const float e0 = __expf(l0 - m), e1 = __expf(l1 - m);
    const float inv = 1.0f / (e0 + e1);
    out[b * 2 + 0] = e0 * inv;
    out[b * 2 + 1] = e1 * inv;
}

extern "C" void kernel_launch(void* const* d_in, const int* in_sizes, int n_in,
                              void* d_out, int out_size, void* d_ws, size_t ws_size,
                              hipStream_t stream)
{
    const float* x   = (const float*)d_in[0];
    const float* W1f = (const float*)d_in[1];
    const float* U1f = (const float*)d_in[2];
    const float* b1f = (const float*)d_in[3];
    const float* W1b = (const float*)d_in[4];
    const float* U1b = (const float*)d_in[5];
    const float* b1b = (const float*)d_in[6];
    const float* W2f = (const float*)d_in[7];
    const float* U2f = (const float*)d_in[8];
    const float* b2f = (const float*)d_in[9];
    const float* W2b = (const float*)d_in[10];
    const float* U2b = (const float*)d_in[11];
    const float* b2b = (const float*)d_in[12];
    const float* W3f = (const float*)d_in[13];
    const float* U3f = (const float*)d_in[14];
    const float* b3f = (const float*)d_in[15];
    const float* W3b = (const float*)d_in[16];
    const float* U3b = (const float*)d_in[17];
    const float* b3b = (const float*)d_in[18];
    const float* Wd1 = (const float*)d_in[19];
    const float* bd1 = (const float*)d_in[20];
    const float* Wd2 = (const float*)d_in[21];
    const float* bd2 = (const float*)d_in[22];

    // workspace: exactly the R2-R5-proven 96 MB + 128 KB footprint
    char* ws = (char*)d_ws;
    void*  l1out = (void*)ws;                                  // [T][B][128] bf16 = 64 MB
    void*  l2out = (void*)(ws + (size_t)64 * 1024 * 1024);     // [T][B][64]  bf16 = 32 MB
    float* h3    = (float*)(ws + (size_t)96 * 1024 * 1024);    // [B][32] fp32 = 128 KB
    float* out   = (float*)d_out;

    dim3 grid(BATCH / 16, 2);

    lstm_fused<64, 64, true, true>     // 4 waves/block
        <<<grid, 256, 0, stream>>>(x, W1f, U1f, b1f, W1b, U1b, b1b, l1out);
    lstm_fused<128, 32, false, true>   // 2 waves/block
        <<<grid, 128, 0, stream>>>(l1out, W2f, U2f, b2f, W2b, U2b, b2b, l2out);
    lstm_fused<64, 16, false, false>   // 1 wave/block, barrier-free
        <<<grid, 64, 0, stream>>>(l2out, W3f, U3f, b3f, W3b, U3b, b3b, h3);
    dense_head<<<dim3(BATCH / 256), 256, 0, stream>>>(h3, Wd1, bd1, Wd2, bd2, out);
}